// Round 11
// baseline (124.989 us; speedup 1.0000x reference)
//
#include <hip/hip_runtime.h>
#include <hip/hip_bf16.h>
#include <math.h>

#define DIM 1024
#define NB  4096      // B
#define N2  8192      // 2B
#define BM  128       // tile dim
#define NT  64        // N2 / BM
#define NTILES 2080   // NT*(NT+1)/2

typedef float f32x4 __attribute__((ext_vector_type(4)));
typedef long  i64x2 __attribute__((ext_vector_type(2)));

__device__ __forceinline__ void gload_lds16(const unsigned char* g, unsigned char* l) {
    __builtin_amdgcn_global_load_lds((__attribute__((address_space(1))) void*)(g),
                                     (__attribute__((address_space(3))) void*)(l),
                                     16, 0, 0);
}

// fp8 e4m3fn encode, round-to-nearest-even (manual fallback)
__device__ __forceinline__ unsigned char to_fp8(float x) {
    unsigned int u = __float_as_uint(x);
    unsigned char s = (unsigned char)((u >> 24) & 0x80);
    int e = (int)((u >> 23) & 0xFF) - 127;
    unsigned int m = u & 0x7FFFFF;
    if (e >= -6) {
        if (e > 8) return s | 0x7E;
        unsigned int keep = m >> 20;
        unsigned int rest = m & 0xFFFFF;
        if (rest > 0x80000u || (rest == 0x80000u && (keep & 1))) keep++;
        unsigned int v = ((unsigned int)(e + 7) << 3) + keep;
        if (v >= 0x7F) v = 0x7E;
        return s | (unsigned char)v;
    }
    if (e < -10) return s;
    int drop = 14 - e;
    unsigned int sig = 0x800000u | m;
    unsigned int keep = sig >> drop;
    unsigned int rem  = sig & ((1u << drop) - 1u);
    unsigned int half = 1u << (drop - 1);
    if (rem > half || (rem == half && (keep & 1))) keep++;
    return s | (unsigned char)keep;
}

__device__ __forceinline__ unsigned int pk4_fp8(float a, float b, float c, float d) {
#if __has_builtin(__builtin_amdgcn_cvt_pk_fp8_f32)
    unsigned int q = 0;
    q = (unsigned int)__builtin_amdgcn_cvt_pk_fp8_f32(a, b, (int)q, false);
    q = (unsigned int)__builtin_amdgcn_cvt_pk_fp8_f32(c, d, (int)q, true);
    return q;
#else
    union { unsigned int u; unsigned char cc[4]; } q;
    q.cc[0] = to_fp8(a); q.cc[1] = to_fp8(b); q.cc[2] = to_fp8(c); q.cc[3] = to_fp8(d);
    return q.u;
#endif
}

// ---------------- Kernel 1: normalize rows, emit fp8 z (k-interleaved), pos --
// Column permutation within each 64-block: global col j -> stored byte
//   j<32: (j>>3)*16 + (j&7);  j>=32: ((j-32)>>3)*16 + 8 + ((j-32)&7)
// so one 16B granule G of a row holds k in {8G..8G+7} U {32+8G..32+8G+7}:
// one ds_read_b128 yields BOTH K=32 MFMA slices. Same perm on A and B.
__global__ __launch_bounds__(256) void norm_kernel(
    const float* __restrict__ p1, const float* __restrict__ p2,
    unsigned char* __restrict__ zq, float* __restrict__ pos)
{
    const int r = blockIdx.x;
    const int t = threadIdx.x;
    const float4 x1 = ((const float4*)(p1 + (size_t)r * DIM))[t];
    const float4 x2 = ((const float4*)(p2 + (size_t)r * DIM))[t];
    float s1  = x1.x*x1.x + x1.y*x1.y + x1.z*x1.z + x1.w*x1.w;
    float s2  = x2.x*x2.x + x2.y*x2.y + x2.z*x2.z + x2.w*x2.w;
    float s12 = x1.x*x2.x + x1.y*x2.y + x1.z*x2.z + x1.w*x2.w;
#pragma unroll
    for (int off = 1; off < 64; off <<= 1) {
        s1  += __shfl_xor(s1,  off);
        s2  += __shfl_xor(s2,  off);
        s12 += __shfl_xor(s12, off);
    }
    __shared__ float ls[3][4];
    const int wid = t >> 6;
    if ((t & 63) == 0) { ls[0][wid] = s1; ls[1][wid] = s2; ls[2][wid] = s12; }
    __syncthreads();
    s1  = ls[0][0] + ls[0][1] + ls[0][2] + ls[0][3];
    s2  = ls[1][0] + ls[1][1] + ls[1][2] + ls[1][3];
    s12 = ls[2][0] + ls[2][1] + ls[2][2] + ls[2][3];
    const float rn1 = 1.0f / fmaxf(sqrtf(s1), 1e-12f);
    const float rn2 = 1.0f / fmaxf(sqrtf(s2), 1e-12f);
    if (t == 0) pos[r] = s12 * rn1 * rn2;

    const int j0 = (t << 2) & 63;       // col within 64-block
    const int kb = t >> 4;              // 64-block index
    const int pb = (j0 < 32) ? (((j0 >> 3) << 4) + (j0 & 7))
                             : ((((j0 - 32) >> 3) << 4) + 8 + ((j0 - 32) & 7));
    const size_t off8 = (size_t)kb * 64 + pb;
    *(unsigned int*)(zq + (size_t)r * DIM + off8) =
        pk4_fp8(x1.x * rn1, x1.y * rn1, x1.z * rn1, x1.w * rn1);
    *(unsigned int*)(zq + (size_t)(NB + r) * DIM + off8) =
        pk4_fp8(x2.x * rn2, x2.y * rn2, x2.z * rn2, x2.w * rn2);
}

// ------- Kernel 2: 128^2 fp8 symmetric z.z^T, 4 waves (2x2), 64x64/wave -----
// 256-thread blocks, LDS 32 KB -> 4-5 blocks co-resident per CU with
// INDEPENDENT barriers: one block's MFMA burst overlaps another's LDS/stage
// phase (1024-thread blocks never co-resided: R8/R10 occupancy ~29%).
// LDS bank fix: granule g of LDS row R lives at slot g^((R>>1)&3) — achieved
// by pre-swizzling the per-lane GLOBAL source (linear gload dest, rule #21)
// and XOR-ing the ds_read address. Lanes 0-15 then cover all 8 bank-quads
// evenly (was: 8-way aliasing on quads {0-3,16-19}).
__global__ __launch_bounds__(256, 5) void sim_kernel(
    const unsigned char* __restrict__ zq,
    float* __restrict__ partials,    // [N2][NT]
    float* __restrict__ lup)         // [NT*NT], rt<=ct slots only
{
    __shared__ __align__(16) unsigned char buf[2][2][BM * 64]; // 32 KB
    const int t    = threadIdx.x;
    const int lane = t & 63;
    const int wid  = t >> 6;       // 0..3
    const int wr   = wid >> 1;     // 0..1 (64-row half)
    const int wc   = wid & 1;      // 0..1 (64-col half)

    const int bid = blockIdx.x;
    const int job = (bid & 7) * (NTILES / 8) + (bid >> 3);   // bijective XCD swizzle
    int rt = 0;
    while ((rt + 1) * NT - (((rt + 1) * rt) >> 1) <= job) ++rt;
    const int ct = rt + job - (rt * NT - ((rt * (rt - 1)) >> 1));
    const bool isdiag = (rt == ct);
    const int row0 = rt * BM;
    const int col0 = ct * BM;

    const int fr = lane & 15;                  // fragment row (A) / col (B)
    const int kg = lane >> 4;                  // k-group 0..3
    const int cb = ((kg ^ ((fr >> 1) & 3)) << 4);  // swizzled granule byte
    const int aoff = (((wr << 6) + fr) << 6) + cb;
    const int boff = (((wc << 6) + fr) << 6) + cb;

    // staging: chunk = 16 rows x 64B = 1KB; lane: row l>>2, granule slot l&3;
    // source granule = (l&3) ^ ((l>>3)&3)  [= slot ^ rowclass, involution]
    const int srow = lane >> 2;
    const int sgr  = (((lane & 3) ^ ((lane >> 3) & 3)) << 4);
    const unsigned char* arow = zq + (size_t)(row0 + srow) * DIM + sgr;
    const unsigned char* bcol = zq + (size_t)(col0 + srow) * DIM + sgr;

    // wave wid stages chunks (wid*4+c), c=0..3: ch 0-7 = A rows 16ch,
    // ch 8-15 = B rows 16(ch-8)
#define STAGE(bsel, ktv) do { \
    _Pragma("unroll") \
    for (int c = 0; c < 4; ++c) { \
        const int ch  = (wid << 2) | c; \
        const int mat = ch >> 3; \
        const int rb  = (ch & 7) << 4; \
        const unsigned char* src = (mat ? bcol : arow) + (size_t)rb * DIM + (ktv) * 64; \
        gload_lds16(src, &buf[bsel][mat][(ch & 7) << 10]); \
    } \
} while (0)

    f32x4 acc[4][4] = {};

    STAGE(0, 0);
    __syncthreads();

#pragma unroll
    for (int kt = 0; kt < 16; ++kt) {
        const int cur = kt & 1;
        if (kt < 15) STAGE(cur ^ 1, kt + 1);
        const unsigned char* Ab = &buf[cur][0][0] + aoff;
        const unsigned char* Bb = &buf[cur][1][0] + boff;
        i64x2 bq[4];
#pragma unroll
        for (int n = 0; n < 4; ++n)
            bq[n] = *(const i64x2*)(Bb + (n << 10));
#pragma unroll
        for (int m = 0; m < 4; ++m) {
            const i64x2 aq = *(const i64x2*)(Ab + (m << 10));
#pragma unroll
            for (int n = 0; n < 4; ++n)
                acc[m][n] = __builtin_amdgcn_mfma_f32_16x16x32_fp8_fp8(aq[0], bq[n][0], acc[m][n], 0, 0, 0);
#pragma unroll
            for (int n = 0; n < 4; ++n)
                acc[m][n] = __builtin_amdgcn_mfma_f32_16x16x32_fp8_fp8(aq[1], bq[n][1], acc[m][n], 0, 0, 0);
        }
        __syncthreads();
    }
#undef STAGE

    // ---- epilogue: C/D layout col=lane&15, row=(lane>>4)*4+reg ----
    float* rowsum = (float*)&buf[0][0][0];  // [128]
    float* colsum = rowsum + 128;           // [128]
    float* lured  = colsum + 128;           // [4]

    if (t < 128) rowsum[t] = 0.0f;
    else         colsum[t - 128] = 0.0f;
    __syncthreads();

    const int  rsub  = (lane >> 4) << 2;
    const int  csub  = lane & 15;
    const bool inreg = (ct < 16) || (rt >= 16 && ct >= 16 && ct < 32); // lunif blocks
    const int  rbase = row0 + (wr << 6);
    const int  cbase = col0 + (wc << 6);

    float lu = 0.0f;
    float cs[4] = {0.0f, 0.0f, 0.0f, 0.0f};
#pragma unroll
    for (int m = 0; m < 4; ++m) {
        float rs[4] = {0.0f, 0.0f, 0.0f, 0.0f};
#pragma unroll
        for (int n = 0; n < 4; ++n) {
            const int gcol = cbase + (n << 4) + csub;
#pragma unroll
            for (int r = 0; r < 4; ++r) {
                const int grow = rbase + (m << 4) + rsub + r;
                const float s = acc[m][n][r];
                float e = __expf(10.0f * s);
                if (isdiag) e = (grow != gcol) ? e : 0.0f;
                rs[r] += e;
                cs[n] += e;
                if (inreg && (!isdiag || gcol > grow)) {
                    const float d2 = fmaxf(2.0f - 2.0f * s, 0.0f);
                    lu += __expf(-2.0f * d2);
                }
            }
        }
#pragma unroll
        for (int off = 1; off < 16; off <<= 1) {
#pragma unroll
            for (int r = 0; r < 4; ++r) rs[r] += __shfl_xor(rs[r], off);
        }
        if ((lane & 15) == 0) {
#pragma unroll
            for (int r = 0; r < 4; ++r)
                atomicAdd(&rowsum[(wr << 6) + (m << 4) + rsub + r], rs[r]); // 2 adds/slot
        }
    }
    if (!isdiag) {
#pragma unroll
        for (int off = 16; off < 64; off <<= 1) {
#pragma unroll
            for (int n = 0; n < 4; ++n) cs[n] += __shfl_xor(cs[n], off);
        }
        if (lane < 16) {
#pragma unroll
            for (int n = 0; n < 4; ++n)
                atomicAdd(&colsum[(wc << 6) + (n << 4) + lane], cs[n]);     // 2 adds/slot
        }
    }
#pragma unroll
    for (int off = 1; off < 64; off <<= 1) lu += __shfl_xor(lu, off);
    if (lane == 0) lured[wid] = lu;
    __syncthreads();

    if (t == 0) lup[(rt << 6) | ct] = lured[0] + lured[1] + lured[2] + lured[3];
    if (t < 128) partials[(size_t)(row0 + t) * NT + ct] = rowsum[t];
    else if (!isdiag) partials[(size_t)(col0 + t - 128) * NT + rt] = colsum[t - 128];
}

// --------- Kernel 3a: per-row denom -> log, 128 rows per block --------------
__global__ __launch_bounds__(128) void logred_kernel(
    const float* __restrict__ partials, double* __restrict__ red_log)
{
    const int t   = threadIdx.x;
    const int row = blockIdx.x * 128 + t;
    const float* p = partials + (size_t)row * NT;
    float dsum = 0.0f;
#pragma unroll
    for (int i = 0; i < NT; ++i) dsum += p[i];
    double l = log((double)dsum);
    __shared__ double sd[128];
    sd[t] = l;
    __syncthreads();
    for (int s = 64; s > 0; s >>= 1) {
        if (t < s) sd[t] += sd[t + s];
        __syncthreads();
    }
    if (t == 0) red_log[blockIdx.x] = sd[0];
}

// --------- Kernel 3b: final scalars --------------------------------------
__global__ __launch_bounds__(256) void final_kernel(
    const double* __restrict__ red_log, const float* __restrict__ pos,
    const float* __restrict__ lup, float* __restrict__ out)
{
    const int t = threadIdx.x;
    double dlog = 0.0, dpos = 0.0, ds1 = 0.0, ds2 = 0.0;
    if (t < 64) dlog = red_log[t];
    for (int i = t; i < NB; i += 256) dpos += (double)pos[i];
    for (int i = t; i < NT * NT; i += 256) {
        const int rt = i >> 6, ct = i & 63;
        if (rt > ct) continue;                 // only upper-tri tiles written
        const double v = (double)lup[i];
        if (rt < 16 && ct < 16) ds1 += v;
        else if (rt >= 16 && rt < 32 && ct >= 16 && ct < 32) ds2 += v;
    }
    __shared__ double sd[4][256];
    sd[0][t] = dlog; sd[1][t] = dpos; sd[2][t] = ds1; sd[3][t] = ds2;
    __syncthreads();
    for (int s = 128; s > 0; s >>= 1) {
        if (t < s) {
            sd[0][t] += sd[0][t + s]; sd[1][t] += sd[1][t + s];
            sd[2][t] += sd[2][t + s]; sd[3][t] += sd[3][t + s];
        }
        __syncthreads();
    }
    if (t == 0) {
        const double mean_pos = sd[1][0] / (double)NB;
        const double loss   = sd[0][0] / (double)N2 - mean_pos * 10.0;   // /TEMP
        const double lalign = 2.0 - 2.0 * mean_pos;
        const double C      = 2048.0 * 2047.0 * 0.5;
        const double lunif  = 0.5 * (log(sd[2][0] / C) + log(sd[3][0] / C));
        out[0] = (float)loss;
        out[1] = (float)lalign;
        out[2] = (float)lunif;
    }
}

extern "C" void kernel_launch(void* const* d_in, const int* in_sizes, int n_in,
                              void* d_out, int out_size, void* d_ws, size_t ws_size,
                              hipStream_t stream) {
    const float* p1 = (const float*)d_in[0];
    const float* p2 = (const float*)d_in[1];
    float* out = (float*)d_out;

    char* ws = (char*)d_ws;
    unsigned char* zq = (unsigned char*)ws;                               // 8 MB
    float*  partials  = (float*)(ws + ((size_t)8 << 20));                 // 2 MB [8192][64]
    float*  pos       = (float*)(ws + ((size_t)10 << 20));                // 16 KB
    float*  lup       = (float*)(ws + ((size_t)10 << 20) + 16384);        // 16 KB
    double* red_log   = (double*)(ws + ((size_t)10 << 20) + 32768);       // 512 B

    hipLaunchKernelGGL(norm_kernel,   dim3(NB),     dim3(256), 0, stream, p1, p2, zq, pos);
    hipLaunchKernelGGL(sim_kernel,    dim3(NTILES), dim3(256), 0, stream, zq, partials, lup);
    hipLaunchKernelGGL(logred_kernel, dim3(64),     dim3(128), 0, stream, partials, red_log);
    hipLaunchKernelGGL(final_kernel,  dim3(1),      dim3(256), 0, stream, red_log, pos, lup, out);
}

// Round 12
// 110.534 us; speedup vs baseline: 1.1308x; 1.1308x over previous
//
#include <hip/hip_runtime.h>
#include <hip/hip_bf16.h>
#include <math.h>

#define DIM 1024
#define NB  4096      // B
#define N2  8192      // 2B
#define NJOBS 1056    // Σ_{a=0}^{31}(64-2a): tiles (a,v), v>=2a
#define PS  96        // partials stride: 64 col-tile slots + 32 colsum slots

typedef float f32x4 __attribute__((ext_vector_type(4)));
typedef long  i64x2 __attribute__((ext_vector_type(2)));

__device__ __forceinline__ void gload_lds16(const unsigned char* g, unsigned char* l) {
    __builtin_amdgcn_global_load_lds((__attribute__((address_space(1))) void*)(g),
                                     (__attribute__((address_space(3))) void*)(l),
                                     16, 0, 0);
}

// fp8 e4m3fn encode, round-to-nearest-even (manual fallback)
__device__ __forceinline__ unsigned char to_fp8(float x) {
    unsigned int u = __float_as_uint(x);
    unsigned char s = (unsigned char)((u >> 24) & 0x80);
    int e = (int)((u >> 23) & 0xFF) - 127;
    unsigned int m = u & 0x7FFFFF;
    if (e >= -6) {
        if (e > 8) return s | 0x7E;
        unsigned int keep = m >> 20;
        unsigned int rest = m & 0xFFFFF;
        if (rest > 0x80000u || (rest == 0x80000u && (keep & 1))) keep++;
        unsigned int v = ((unsigned int)(e + 7) << 3) + keep;
        if (v >= 0x7F) v = 0x7E;
        return s | (unsigned char)v;
    }
    if (e < -10) return s;
    int drop = 14 - e;
    unsigned int sig = 0x800000u | m;
    unsigned int keep = sig >> drop;
    unsigned int rem  = sig & ((1u << drop) - 1u);
    unsigned int half = 1u << (drop - 1);
    if (rem > half || (rem == half && (keep & 1))) keep++;
    return s | (unsigned char)keep;
}

__device__ __forceinline__ unsigned int pk4_fp8(float a, float b, float c, float d) {
#if __has_builtin(__builtin_amdgcn_cvt_pk_fp8_f32)
    unsigned int q = 0;
    q = (unsigned int)__builtin_amdgcn_cvt_pk_fp8_f32(a, b, (int)q, false);
    q = (unsigned int)__builtin_amdgcn_cvt_pk_fp8_f32(c, d, (int)q, true);
    return q;
#else
    union { unsigned int u; unsigned char cc[4]; } q;
    q.cc[0] = to_fp8(a); q.cc[1] = to_fp8(b); q.cc[2] = to_fp8(c); q.cc[3] = to_fp8(d);
    return q.u;
#endif
}

// ---------------- Kernel 1: normalize rows, emit fp8 z (k-interleaved), pos --
// Column permutation within each 64-block: global col j -> stored byte
//   j<32: (j>>3)*16 + (j&7);  j>=32: ((j-32)>>3)*16 + 8 + ((j-32)&7)
// One 16B granule G of a row holds k in {8G..8G+7} U {32+8G..32+8G+7}: one
// ds_read_b128 yields BOTH K=32 MFMA slices. Same perm on A and B => cancels.
__global__ __launch_bounds__(256) void norm_kernel(
    const float* __restrict__ p1, const float* __restrict__ p2,
    unsigned char* __restrict__ zq, float* __restrict__ pos)
{
    const int r = blockIdx.x;
    const int t = threadIdx.x;
    const float4 x1 = ((const float4*)(p1 + (size_t)r * DIM))[t];
    const float4 x2 = ((const float4*)(p2 + (size_t)r * DIM))[t];
    float s1  = x1.x*x1.x + x1.y*x1.y + x1.z*x1.z + x1.w*x1.w;
    float s2  = x2.x*x2.x + x2.y*x2.y + x2.z*x2.z + x2.w*x2.w;
    float s12 = x1.x*x2.x + x1.y*x2.y + x1.z*x2.z + x1.w*x2.w;
#pragma unroll
    for (int off = 1; off < 64; off <<= 1) {
        s1  += __shfl_xor(s1,  off);
        s2  += __shfl_xor(s2,  off);
        s12 += __shfl_xor(s12, off);
    }
    __shared__ float ls[3][4];
    const int wid = t >> 6;
    if ((t & 63) == 0) { ls[0][wid] = s1; ls[1][wid] = s2; ls[2][wid] = s12; }
    __syncthreads();
    s1  = ls[0][0] + ls[0][1] + ls[0][2] + ls[0][3];
    s2  = ls[1][0] + ls[1][1] + ls[1][2] + ls[1][3];
    s12 = ls[2][0] + ls[2][1] + ls[2][2] + ls[2][3];
    const float rn1 = 1.0f / fmaxf(sqrtf(s1), 1e-12f);
    const float rn2 = 1.0f / fmaxf(sqrtf(s2), 1e-12f);
    if (t == 0) pos[r] = s12 * rn1 * rn2;

    const int j0 = (t << 2) & 63;       // col within 64-block
    const int kb = t >> 4;              // 64-block index
    const int pb = (j0 < 32) ? (((j0 >> 3) << 4) + (j0 & 7))
                             : ((((j0 - 32) >> 3) << 4) + 8 + ((j0 - 32) & 7));
    const size_t off8 = (size_t)kb * 64 + pb;
    *(unsigned int*)(zq + (size_t)r * DIM + off8) =
        pk4_fp8(x1.x * rn1, x1.y * rn1, x1.z * rn1, x1.w * rn1);
    *(unsigned int*)(zq + (size_t)(NB + r) * DIM + off8) =
        pk4_fp8(x2.x * rn2, x2.y * rn2, x2.z * rn2, x2.w * rn2);
}

// ------- Kernel 2: 256x128 fp8 symmetric z.z^T tiles, 8 waves (4x2) ---------
// Tile (a,v): A rows [256a,256a+256) (units 2a,2a+1), B cols [128v,128v+128)
// (unit v), valid v>=2a (1056 jobs = 8x132, XCD-chunked a-major).
// Per-element accounting (handles diagonal/below-diagonal uniformly):
//   e masked at grow==gcol; rowsum iff unit(grow)<=unit(gcol) -> slot v;
//   colsum iff unit(grow)<unit(gcol) -> slot 64+a; lunif iff gcol>grow + region.
// 512-thr blocks, LDS 48 KB, acc=64 -> 2 blocks/CU co-resident (independent
// barriers break the stage/read/MFMA convoy of a single lockstep block).
__global__ __launch_bounds__(512, 4) void sim_kernel(
    const unsigned char* __restrict__ zq,
    float* __restrict__ partials,    // [N2][PS], zeroed before launch
    float* __restrict__ lup)         // [NJOBS]
{
    __shared__ __align__(16) unsigned char bufA[2][256 * 64]; // 32 KB
    __shared__ __align__(16) unsigned char bufB[2][128 * 64]; // 16 KB

    const int t    = threadIdx.x;
    const int lane = t & 63;
    const int wid  = t >> 6;       // 0..7
    const int wr   = wid >> 1;     // 0..3 (64-row strip of 256)
    const int wc   = wid & 1;      // 0..1 (64-col strip of 128)

    const int bid = blockIdx.x;
    const int job = (bid & 7) * (NJOBS / 8) + (bid >> 3);   // bijective XCD chunk
    int a = 0;                                   // start(a) = a*(65-a)
    while ((a + 1) * (64 - a) <= job) ++a;
    const int v = 2 * a + (job - a * (65 - a));
    const int row0 = a << 8;
    const int col0 = v << 7;

    const int fr = lane & 15;      // fragment row (A) / col (B)
    const int kg = lane >> 4;      // k-group 0..3
    const int cb = ((kg ^ ((fr >> 1) & 3)) << 4);   // bank-swizzled granule
    const int aoff = (((wr << 6) + fr) << 6) + cb;
    const int boff = (((wc << 6) + fr) << 6) + cb;

    // staging: 24 chunks of 16 rows x 64B (A: 0-15, B: 16-23), 3 per wave;
    // lane: row l>>2, LDS slot l&3, global granule (l&3)^((l>>3)&3) (involution)
    const int srow = lane >> 2;
    const int sgr  = (((lane & 3) ^ ((lane >> 3) & 3)) << 4);

#define STAGE(bsel, ktv) do { \
    _Pragma("unroll") \
    for (int c = 0; c < 3; ++c) { \
        const int ch  = wid * 3 + c; \
        const int isB = ch >> 4; \
        const int chl = ch & 15; \
        const unsigned char* src = zq + (size_t)((isB ? col0 : row0) + (chl << 4) + srow) * DIM \
                                      + (ktv) * 64 + sgr; \
        gload_lds16(src, (isB ? &bufB[bsel][chl << 10] : &bufA[bsel][chl << 10])); \
    } \
} while (0)

    f32x4 acc[4][4] = {};

    STAGE(0, 0);
    __syncthreads();

#pragma unroll
    for (int kt = 0; kt < 16; ++kt) {
        const int cur = kt & 1;
        if (kt < 15) STAGE(cur ^ 1, kt + 1);
        const unsigned char* Ab = &bufA[cur][0] + aoff;
        const unsigned char* Bb = &bufB[cur][0] + boff;
        i64x2 bq[4];
#pragma unroll
        for (int n = 0; n < 4; ++n)
            bq[n] = *(const i64x2*)(Bb + (n << 10));
#pragma unroll
        for (int m = 0; m < 4; ++m) {
            const i64x2 aq = *(const i64x2*)(Ab + (m << 10));
#pragma unroll
            for (int n = 0; n < 4; ++n)
                acc[m][n] = __builtin_amdgcn_mfma_f32_16x16x32_fp8_fp8(aq[0], bq[n][0], acc[m][n], 0, 0, 0);
#pragma unroll
            for (int n = 0; n < 4; ++n)
                acc[m][n] = __builtin_amdgcn_mfma_f32_16x16x32_fp8_fp8(aq[1], bq[n][1], acc[m][n], 0, 0, 0);
        }
        __syncthreads();
    }
#undef STAGE

    // ---- epilogue: C/D layout col=lane&15, row=(lane>>4)*4+reg ----
    float* rsum2 = (float*)&bufA[0][0];     // [256][2] per-(row,wc), all written
    float* csum4 = rsum2 + 512;             // [128][4] per-(col,wr), all written
    float* lured = csum4 + 512;             // [8]

    const int rsub = (lane >> 4) << 2;
    const int csub = lane & 15;

    float lu = 0.0f;
    float cs[4] = {0.0f, 0.0f, 0.0f, 0.0f};
#pragma unroll
    for (int m = 0; m < 4; ++m) {
        float rs[4] = {0.0f, 0.0f, 0.0f, 0.0f};
#pragma unroll
        for (int n = 0; n < 4; ++n) {
            const int gcol = col0 + (wc << 6) + (n << 4) + csub;
            const int ucol = gcol >> 7;
#pragma unroll
            for (int r = 0; r < 4; ++r) {
                const int grow = row0 + (wr << 6) + (m << 4) + rsub + r;
                const int urow = grow >> 7;
                const float s = acc[m][n][r];
                float e = __expf(10.0f * s);
                e = (grow != gcol) ? e : 0.0f;
                rs[r] += (urow <= ucol) ? e : 0.0f;
                cs[n] += (urow <  ucol) ? e : 0.0f;
                // lunif: strict upper, same 2048-block, within z_i
                const bool inr = ((grow >> 11) == (gcol >> 11)) && ((grow >> 12) == 0);
                if (inr && (gcol > grow)) {
                    const float d2 = fmaxf(2.0f - 2.0f * s, 0.0f);
                    lu += __expf(-2.0f * d2);
                }
            }
        }
#pragma unroll
        for (int off = 1; off < 16; off <<= 1) {
#pragma unroll
            for (int r = 0; r < 4; ++r) rs[r] += __shfl_xor(rs[r], off);
        }
        if ((lane & 15) == 0) {
#pragma unroll
            for (int r = 0; r < 4; ++r)
                rsum2[((wr << 6) + (m << 4) + rsub + r) * 2 + wc] = rs[r];
        }
    }
#pragma unroll
    for (int off = 16; off < 64; off <<= 1) {
#pragma unroll
        for (int n = 0; n < 4; ++n) cs[n] += __shfl_xor(cs[n], off);
    }
    if (lane < 16) {
#pragma unroll
        for (int n = 0; n < 4; ++n)
            csum4[((wc << 6) + (n << 4) + lane) * 4 + wr] = cs[n];
    }
#pragma unroll
    for (int off = 1; off < 64; off <<= 1) lu += __shfl_xor(lu, off);
    if (lane == 0) lured[wid] = lu;
    __syncthreads();

    if (t == 0) {
        float s = 0.0f;
#pragma unroll
        for (int w = 0; w < 8; ++w) s += lured[w];
        lup[job] = s;
    }
    if (t < 256) {
        partials[(size_t)(row0 + t) * PS + v] = rsum2[t * 2] + rsum2[t * 2 + 1];
    } else if (t < 384) {
        const int j2 = t - 256;
        const float* p = csum4 + j2 * 4;
        partials[(size_t)(col0 + j2) * PS + 64 + a] = ((p[0] + p[1]) + p[2]) + p[3];
    }
}

// --------- Kernel 3a: per-row denom -> log, 128 rows per block --------------
__global__ __launch_bounds__(128) void logred_kernel(
    const float* __restrict__ partials, double* __restrict__ red_log)
{
    const int t   = threadIdx.x;
    const int row = blockIdx.x * 128 + t;
    const float* p = partials + (size_t)row * PS;
    float dsum = 0.0f;
#pragma unroll
    for (int i = 0; i < PS; ++i) dsum += p[i];
    double l = log((double)dsum);
    __shared__ double sd[128];
    sd[t] = l;
    __syncthreads();
    for (int s = 64; s > 0; s >>= 1) {
        if (t < s) sd[t] += sd[t + s];
        __syncthreads();
    }
    if (t == 0) red_log[blockIdx.x] = sd[0];
}

// --------- Kernel 3b: final scalars --------------------------------------
__global__ __launch_bounds__(256) void final_kernel(
    const double* __restrict__ red_log, const float* __restrict__ pos,
    const float* __restrict__ lup, float* __restrict__ out)
{
    const int t = threadIdx.x;
    double dlog = 0.0, dpos = 0.0, ds1 = 0.0, ds2 = 0.0;
    if (t < 64) dlog = red_log[t];
    for (int i = t; i < NB; i += 256) dpos += (double)pos[i];
    for (int i = t; i < NJOBS; i += 256) {
        int a = 0;
        while ((a + 1) * (64 - a) <= i) ++a;
        const int v = 2 * a + (i - a * (65 - a));
        const double val = (double)lup[i];
        if (a < 8 && v < 16) ds1 += val;                       // z_i[:2048] block
        else if (a >= 8 && a < 16 && v >= 16 && v < 32) ds2 += val; // z_i[2048:]
    }
    __shared__ double sd[4][256];
    sd[0][t] = dlog; sd[1][t] = dpos; sd[2][t] = ds1; sd[3][t] = ds2;
    __syncthreads();
    for (int s = 128; s > 0; s >>= 1) {
        if (t < s) {
            sd[0][t] += sd[0][t + s]; sd[1][t] += sd[1][t + s];
            sd[2][t] += sd[2][t + s]; sd[3][t] += sd[3][t + s];
        }
        __syncthreads();
    }
    if (t == 0) {
        const double mean_pos = sd[1][0] / (double)NB;
        const double loss   = sd[0][0] / (double)N2 - mean_pos * 10.0;   // /TEMP
        const double lalign = 2.0 - 2.0 * mean_pos;
        const double C      = 2048.0 * 2047.0 * 0.5;
        const double lunif  = 0.5 * (log(sd[2][0] / C) + log(sd[3][0] / C));
        out[0] = (float)loss;
        out[1] = (float)lalign;
        out[2] = (float)lunif;
    }
}

extern "C" void kernel_launch(void* const* d_in, const int* in_sizes, int n_in,
                              void* d_out, int out_size, void* d_ws, size_t ws_size,
                              hipStream_t stream) {
    const float* p1 = (const float*)d_in[0];
    const float* p2 = (const float*)d_in[1];
    float* out = (float*)d_out;

    char* ws = (char*)d_ws;
    unsigned char* zq = (unsigned char*)ws;                               // 8 MB
    float*  partials  = (float*)(ws + ((size_t)8 << 20));                 // 3 MB [8192][96]
    float*  pos       = (float*)(ws + ((size_t)12 << 20));                // 16 KB
    float*  lup       = (float*)(ws + ((size_t)12 << 20) + 16384);        // ~4.2 KB
    double* red_log   = (double*)(ws + ((size_t)12 << 20) + 24576);       // 512 B

    hipMemsetAsync(partials, 0, (size_t)N2 * PS * sizeof(float), stream);
    hipLaunchKernelGGL(norm_kernel,   dim3(NB),    dim3(256), 0, stream, p1, p2, zq, pos);
    hipLaunchKernelGGL(sim_kernel,    dim3(NJOBS), dim3(512), 0, stream, zq, partials, lup);
    hipLaunchKernelGGL(logred_kernel, dim3(64),    dim3(128), 0, stream, partials, red_log);
    hipLaunchKernelGGL(final_kernel,  dim3(1),     dim3(256), 0, stream, red_log, pos, lup, out);
}